// Round 3
// baseline (892.797 us; speedup 1.0000x reference)
//
#include <hip/hip_runtime.h>
#include <hip/hip_bf16.h>
#include <math.h>

typedef unsigned short u16;
typedef __bf16 bf16x8 __attribute__((ext_vector_type(8)));
typedef float f32x4 __attribute__((ext_vector_type(4)));
typedef unsigned short u16x8 __attribute__((ext_vector_type(8)));
typedef unsigned short u16x4 __attribute__((ext_vector_type(4)));
typedef unsigned short u16x2 __attribute__((ext_vector_type(2)));

#define DEV static __device__ __forceinline__

DEV float b2f(u16 v) { unsigned u = ((unsigned)v) << 16; return __builtin_bit_cast(float, u); }
DEV u16 f2bf(float f) {
  unsigned u = __builtin_bit_cast(unsigned, f);
  u += 0x7fffu + ((u >> 16) & 1u);
  return (u16)(u >> 16);
}

DEV void async16(const void* g, void* l) {
  __builtin_amdgcn_global_load_lds(
      (const __attribute__((address_space(1))) void*)g,
      (__attribute__((address_space(3))) void*)l, 16, 0, 0);
}

// ---------------------------------------------------------------------------
// f32 -> bf16 conversion (vectorized), n4 = elements/4
// ---------------------------------------------------------------------------
__global__ __launch_bounds__(256) void cvt_kernel(
    const float* __restrict__ in, u16* __restrict__ out, int n4)
{
  const int i = blockIdx.x * 256 + threadIdx.x;
  if (i < n4) {
    float4 v = ((const float4*)in)[i];
    u16x4 o;
    o[0] = f2bf(v.x); o[1] = f2bf(v.y); o[2] = f2bf(v.z); o[3] = f2bf(v.w);
    ((u16x4*)out)[i] = o;
  }
}

// ---------------------------------------------------------------------------
// CPB bias table (f32 in, into d_out scratch): btbl[h][i][j]=16*sigmoid(tbl[i-j+63][h])
// ---------------------------------------------------------------------------
__global__ __launch_bounds__(64) void cpb_kernel(
    const float* __restrict__ w1, const float* __restrict__ b1,
    const float* __restrict__ w2, float* __restrict__ btbl)
{
  const int h = blockIdx.x;
  const int lane = threadIdx.x;
  __shared__ float tbl[127];
  for (int r = lane; r < 127; r += 64) {
    float rv = (float)(r - 63) * (8.0f / 63.0f);
    float sgn = (rv > 0.f) ? 1.f : ((rv < 0.f) ? -1.f : 0.f);
    float t = sgn * log2f(fabsf(rv) + 1.f) * (1.f / 3.f);
    float acc = 0.f;
    for (int k = 0; k < 512; ++k) {
      float hid = fmaxf(t * w1[k] + b1[k], 0.f);
      acc += hid * w2[h * 512 + k];
    }
    tbl[r] = acc;
  }
  __syncthreads();
  for (int idx = lane; idx < 4096; idx += 64) {
    int i = idx >> 6, j = idx & 63;
    float v = tbl[i - j + 63];
    btbl[h * 4096 + idx] = 16.f / (1.f + __expf(-v));
  }
}

// ---------------------------------------------------------------------------
// GEMM  C[m][n] = sum_k A[m][k] * W[n][k]   (A,W bf16; bias f32; out bf16)
// MODE 0: qkv (roll folded via m_base+global row; scatter + q/v bias)
// MODE 1: proj (+bias)   MODE 2: fc1 (+bias+gelu)   MODE 3: fc2 (+bias)
// ---------------------------------------------------------------------------
template <int MODE>
__global__ __launch_bounds__(256) void gemm_bt(
    const u16* __restrict__ A, const u16* __restrict__ W,
    const float* __restrict__ bias1, const float* __restrict__ bias2,
    u16* __restrict__ out, int M, int N, int K, int m_base)
{
  constexpr int BK = 32;
  __shared__ __attribute__((aligned(16))) u16 lA[128 * BK];
  __shared__ __attribute__((aligned(16))) u16 lB[128 * BK];
  const int tid = threadIdx.x;
  const int wid = tid >> 6;
  const int lane = tid & 63;
  const int m0 = blockIdx.x * 128;
  const int n0 = blockIdx.y * 128;
  const int wm = (wid >> 1) * 64;
  const int wn = (wid & 1) * 64;
  f32x4 acc[4][4] = {};

  const int srow = lane >> 2;
  const int scol = (lane & 3) * 8;

  for (int k0 = 0; k0 < K; k0 += BK) {
    #pragma unroll
    for (int cc = 0; cc < 2; ++cc) {
      const int chunk = wid * 2 + cc;
      const int r = chunk * 16 + srow;
      long ga;
      if constexpr (MODE == 0) {
        const int mg = m_base + m0 + r;
        const int bb = mg >> 12;
        const int p = mg & 4095;
        ga = ((long)bb << 12) + ((p + 32) & 4095);   // cyclic shift folded in
      } else {
        ga = m0 + r;
      }
      async16(A + ga * (long)K + k0 + scol, &lA[chunk * 512]);
      async16(W + (long)(n0 + r) * K + k0 + scol, &lB[chunk * 512]);
    }
    __syncthreads();
    const int frow = lane & 15;
    const int fk = (lane >> 4) * 8;
    bf16x8 fa[4], fb[4];
    #pragma unroll
    for (int t = 0; t < 4; ++t) {
      fa[t] = *(const bf16x8*)&lA[(wm + t * 16 + frow) * BK + fk];
      fb[t] = *(const bf16x8*)&lB[(wn + t * 16 + frow) * BK + fk];
    }
    #pragma unroll
    for (int mi = 0; mi < 4; ++mi)
      #pragma unroll
      for (int ni = 0; ni < 4; ++ni)
        acc[mi][ni] = __builtin_amdgcn_mfma_f32_16x16x32_bf16(fa[mi], fb[ni], acc[mi][ni], 0, 0, 0);
    __syncthreads();
  }

  const int lrow = (lane >> 4) * 4;
  const int lcol = lane & 15;
  #pragma unroll
  for (int mi = 0; mi < 4; ++mi) {
    #pragma unroll
    for (int ni = 0; ni < 4; ++ni) {
      const int n = n0 + wn + ni * 16 + lcol;
      #pragma unroll
      for (int r = 0; r < 4; ++r) {
        const int m = m0 + wm + mi * 16 + lrow + r;
        float v = acc[mi][ni][r];
        if constexpr (MODE == 0) {
          const int which = n >> 9, c = n & 511;
          const int hh = c >> 5, d = c & 31;
          float bias = (which == 0) ? bias1[c] : (which == 2 ? bias2[c] : 0.f);
          const int g = m >> 6, ii = m & 63;
          out[(size_t)which * 8388608 + (size_t)g * 32768 + hh * 2048 + ii * 32 + d] =
              f2bf(v + bias);
        } else if constexpr (MODE == 2) {
          float t = v + bias1[n];
          float ge = 0.5f * t * (1.f + erff(t * 0.70710678118654752f));
          out[(size_t)m * N + n] = f2bf(ge);
        } else {
          out[(size_t)m * N + n] = f2bf(v + bias1[n]);
        }
      }
    }
  }
}

// ---------------------------------------------------------------------------
// Attention: one wave per (local window g, head h). qkvh [3][256][16][64][32] bf16.
// Writes attnout at global row (g0+g)*64+i.
// ---------------------------------------------------------------------------
__global__ __launch_bounds__(64) void attn_kernel(
    const u16* __restrict__ qkv, const float* __restrict__ ls,
    const float* __restrict__ btbl, u16* __restrict__ attn_out, int g0)
{
  const int g = blockIdx.x, h = blockIdx.y, i = threadIdx.x;
  __shared__ __attribute__((aligned(16))) float kn[64][32];
  __shared__ __attribute__((aligned(16))) float vv[64][32];
  const size_t base = (size_t)g * 32768 + (size_t)h * 2048 + (size_t)i * 32;

  float q[32];
  float qs = 0.f;
  {
    const u16x8* p = (const u16x8*)(qkv + base);
    #pragma unroll
    for (int t = 0; t < 4; ++t) {
      u16x8 r = p[t];
      #pragma unroll
      for (int e = 0; e < 8; ++e) { float f = b2f(r[e]); q[t * 8 + e] = f; qs += f * f; }
    }
  }
  const float qinv = 1.f / fmaxf(sqrtf(qs), 1e-12f);
  {
    const u16x8* p = (const u16x8*)(qkv + 8388608 + base);
    float kk[32]; float kssum = 0.f;
    #pragma unroll
    for (int t = 0; t < 4; ++t) {
      u16x8 r = p[t];
      #pragma unroll
      for (int e = 0; e < 8; ++e) { float f = b2f(r[e]); kk[t * 8 + e] = f; kssum += f * f; }
    }
    const float kinv = 1.f / fmaxf(sqrtf(kssum), 1e-12f);
    #pragma unroll
    for (int d = 0; d < 32; ++d) kn[i][d] = kk[d] * kinv;
  }
  {
    const u16x8* p = (const u16x8*)(qkv + 16777216 + base);
    #pragma unroll
    for (int t = 0; t < 4; ++t) {
      u16x8 r = p[t];
      #pragma unroll
      for (int e = 0; e < 8; ++e) vv[i][t * 8 + e] = b2f(r[e]);
    }
  }
  __syncthreads();
  const float sc = __expf(fminf(ls[h], 4.6051701859880914f));
  const float qscale = qinv * sc;
  const float* bt = btbl + h * 4096 + i * 64;
  float s[64];
  #pragma unroll
  for (int j = 0; j < 64; ++j) {
    const float4* kr = (const float4*)&kn[j][0];
    float dot = 0.f;
    #pragma unroll
    for (int dd = 0; dd < 8; ++dd) {
      float4 kv = kr[dd];
      dot += q[dd * 4 + 0] * kv.x + q[dd * 4 + 1] * kv.y +
             q[dd * 4 + 2] * kv.z + q[dd * 4 + 3] * kv.w;
    }
    s[j] = dot * qscale + bt[j];
  }
  if (((g0 + g) & 63) == 63) {
    #pragma unroll
    for (int j = 0; j < 64; ++j)
      if ((i < 32) != (j < 32)) s[j] -= 100.f;
  }
  float mx = s[0];
  #pragma unroll
  for (int j = 1; j < 64; ++j) mx = fmaxf(mx, s[j]);
  float sum = 0.f;
  #pragma unroll
  for (int j = 0; j < 64; ++j) { float e = __expf(s[j] - mx); s[j] = e; sum += e; }
  const float inv = 1.f / sum;
  float o[32];
  #pragma unroll
  for (int d = 0; d < 32; ++d) o[d] = 0.f;
  #pragma unroll
  for (int j = 0; j < 64; ++j) {
    const float4* vr = (const float4*)&vv[j][0];
    const float pj = s[j];
    #pragma unroll
    for (int dd = 0; dd < 8; ++dd) {
      float4 v4 = vr[dd];
      o[dd * 4 + 0] += pj * v4.x; o[dd * 4 + 1] += pj * v4.y;
      o[dd * 4 + 2] += pj * v4.z; o[dd * 4 + 3] += pj * v4.w;
    }
  }
  u16* op = attn_out + ((size_t)((g0 + g) * 64 + i)) * 512 + h * 32;
  #pragma unroll
  for (int t = 0; t < 4; ++t) {
    u16x8 r;
    #pragma unroll
    for (int e = 0; e < 8; ++e) r[e] = f2bf(o[t * 8 + e] * inv);
    *(u16x8*)(op + t * 8) = r;
  }
}

// ---------------------------------------------------------------------------
// LN1: x1h = bf16( x + LN(roll_back(proj_out)) ),  x read as f32
// ---------------------------------------------------------------------------
__global__ __launch_bounds__(256) void ln1_kernel(
    const u16* __restrict__ proj, const float* __restrict__ x,
    const float* __restrict__ w, const float* __restrict__ bb,
    u16* __restrict__ x1h)
{
  const int t = blockIdx.x;
  const int b = t >> 12, l = t & 4095;
  const int p = (l - 32) & 4095;                    // reverse cyclic shift
  const size_t srow = (((size_t)b << 12) + p) << 9;
  const int c0 = threadIdx.x * 2;
  u16x2 pv = *(const u16x2*)(proj + srow + c0);
  float v0 = b2f(pv[0]), v1 = b2f(pv[1]);
  float s = v0 + v1, ss = v0 * v0 + v1 * v1;
  #pragma unroll
  for (int o = 32; o > 0; o >>= 1) { s += __shfl_down(s, o); ss += __shfl_down(ss, o); }
  __shared__ float red[8];
  const int wid = threadIdx.x >> 6, lane = threadIdx.x & 63;
  if (lane == 0) { red[wid] = s; red[4 + wid] = ss; }
  __syncthreads();
  const float S = red[0] + red[1] + red[2] + red[3];
  const float SS = red[4] + red[5] + red[6] + red[7];
  const float mean = S * (1.f / 512.f);
  const float var = SS * (1.f / 512.f) - mean * mean;
  const float rstd = rsqrtf(var + 1e-5f);
  const size_t orow = (size_t)t << 9;
  float2 xv = *(const float2*)(x + orow + c0);
  const float r0 = xv.x + (v0 - mean) * rstd * w[c0] + bb[c0];
  const float r1 = xv.y + (v1 - mean) * rstd * w[c0 + 1] + bb[c0 + 1];
  u16x2 ho; ho[0] = f2bf(r0); ho[1] = f2bf(r1);
  *(u16x2*)(x1h + orow + c0) = ho;
}

// ---------------------------------------------------------------------------
// LN2 (per half, local rows): out = f32( x1 + LN(fc2_out) )
// ---------------------------------------------------------------------------
__global__ __launch_bounds__(256) void ln2_kernel(
    const u16* __restrict__ fc2, const u16* __restrict__ x1h,
    const float* __restrict__ w, const float* __restrict__ bb,
    float* __restrict__ out)
{
  const int t = blockIdx.x;
  const size_t row = (size_t)t << 9;
  const int c0 = threadIdx.x * 2;
  u16x2 pv = *(const u16x2*)(fc2 + row + c0);
  float v0 = b2f(pv[0]), v1 = b2f(pv[1]);
  float s = v0 + v1, ss = v0 * v0 + v1 * v1;
  #pragma unroll
  for (int o = 32; o > 0; o >>= 1) { s += __shfl_down(s, o); ss += __shfl_down(ss, o); }
  __shared__ float red[8];
  const int wid = threadIdx.x >> 6, lane = threadIdx.x & 63;
  if (lane == 0) { red[wid] = s; red[4 + wid] = ss; }
  __syncthreads();
  const float S = red[0] + red[1] + red[2] + red[3];
  const float SS = red[4] + red[5] + red[6] + red[7];
  const float mean = S * (1.f / 512.f);
  const float var = SS * (1.f / 512.f) - mean * mean;
  const float rstd = rsqrtf(var + 1e-5f);
  u16x2 xv = *(const u16x2*)(x1h + row + c0);
  const float r0 = b2f(xv[0]) + (v0 - mean) * rstd * w[c0] + bb[c0];
  const float r1 = b2f(xv[1]) + (v1 - mean) * rstd * w[c0 + 1] + bb[c0 + 1];
  float2 fo; fo.x = r0; fo.y = r1;
  *(float2*)(out + row + c0) = fo;
}

// ---------------------------------------------------------------------------
extern "C" void kernel_launch(void* const* d_in, const int* in_sizes, int n_in,
                              void* d_out, int out_size, void* d_ws, size_t ws_size,
                              hipStream_t stream) {
  const float* x        = (const float*)d_in[0];
  const float* qkv_w    = (const float*)d_in[1];
  const float* q_bias   = (const float*)d_in[2];
  const float* v_bias   = (const float*)d_in[3];
  const float* lscale   = (const float*)d_in[4];
  const float* cpb_w1   = (const float*)d_in[5];
  const float* cpb_b1   = (const float*)d_in[6];
  const float* cpb_w2   = (const float*)d_in[7];
  const float* proj_w   = (const float*)d_in[8];
  const float* proj_b   = (const float*)d_in[9];
  const float* n1w      = (const float*)d_in[10];
  const float* n1b      = (const float*)d_in[11];
  const float* n2w      = (const float*)d_in[12];
  const float* n2b      = (const float*)d_in[13];
  const float* fc1_w    = (const float*)d_in[14];
  const float* fc1_b    = (const float*)d_in[15];
  const float* fc2_w    = (const float*)d_in[16];
  const float* fc2_b    = (const float*)d_in[17];

  if (ws_size < 134217728u) return;   // proven: ws_size >= 128 MiB
  char* ws = (char*)d_ws;
  // bf16 weight copies [0, 6291456)
  u16* wqkv  = (u16*)(ws + 0);              // 1,572,864 B
  u16* wproj = (u16*)(ws + 1572864);        //   524,288 B
  u16* wfc1  = (u16*)(ws + 2097152);        // 2,097,152 B
  u16* wfc2  = (u16*)(ws + 4194304);        // 2,097,152 B
  u16* xbf   = (u16*)(ws + 6291456);        // 33,554,432 B  (dead after qkv GEMMs)
  u16* qkvh  = (u16*)(ws + 39845888);       // 50,331,648 B  per-half [3][256][16][64][32]
  u16* attno = (u16*)(ws + 90177536);       // 33,554,432 B  [32768][512]
  u16* projo = (u16*)(ws + 39845888);       // 33,554,432 B  (reuse qkvh)
  u16* x1h   = (u16*)(ws + 100663296);      // 33,554,432 B  (reuse attno after gemm1)
  u16* hbuf  = (u16*)(ws + 6291456);        // 67,108,864 B  per half (reuse xbf/qkvh/projo)
  u16* fc2oh = (u16*)(ws + 73400320);       // 16,777,216 B  per half
  float* btbl = (float*)d_out;              // 262,144 B scratch; overwritten by ln2
  float* out  = (float*)d_out;

  cvt_kernel<<<16384, 256, 0, stream>>>(x, xbf, 4194304);
  cvt_kernel<<<768, 256, 0, stream>>>(qkv_w, wqkv, 196608);
  cvt_kernel<<<256, 256, 0, stream>>>(proj_w, wproj, 65536);
  cvt_kernel<<<1024, 256, 0, stream>>>(fc1_w, wfc1, 262144);
  cvt_kernel<<<1024, 256, 0, stream>>>(fc2_w, wfc2, 262144);
  cpb_kernel<<<16, 64, 0, stream>>>(cpb_w1, cpb_b1, cpb_w2, btbl);

  for (int half = 0; half < 2; ++half) {
    gemm_bt<0><<<dim3(128, 12), 256, 0, stream>>>(
        xbf, wqkv, q_bias, v_bias, qkvh, 16384, 1536, 512, half * 16384);
    attn_kernel<<<dim3(256, 16), 64, 0, stream>>>(qkvh, lscale, btbl, attno, half * 256);
  }
  gemm_bt<1><<<dim3(256, 4), 256, 0, stream>>>(
      attno, wproj, proj_b, nullptr, projo, 32768, 512, 512, 0);
  ln1_kernel<<<32768, 256, 0, stream>>>(projo, x, n1w, n1b, x1h);
  for (int half = 0; half < 2; ++half) {
    const u16* a2 = x1h + (size_t)half * 8388608;
    gemm_bt<2><<<dim3(128, 16), 256, 0, stream>>>(
        a2, wfc1, fc1_b, nullptr, hbuf, 16384, 2048, 512, 0);
    gemm_bt<3><<<dim3(128, 4), 256, 0, stream>>>(
        hbuf, wfc2, fc2_b, nullptr, fc2oh, 16384, 512, 2048, 0);
    ln2_kernel<<<16384, 256, 0, stream>>>(
        fc2oh, a2, n2w, n2b, out + (size_t)half * 8388608);
  }
}

// Round 4
// 680.823 us; speedup vs baseline: 1.3113x; 1.3113x over previous
//
#include <hip/hip_runtime.h>
#include <hip/hip_bf16.h>
#include <math.h>

typedef unsigned short u16;
typedef __bf16 bf16x8 __attribute__((ext_vector_type(8)));
typedef float f32x4 __attribute__((ext_vector_type(4)));
typedef unsigned short u16x8 __attribute__((ext_vector_type(8)));
typedef unsigned short u16x4 __attribute__((ext_vector_type(4)));
typedef unsigned short u16x2 __attribute__((ext_vector_type(2)));

#define DEV static __device__ __forceinline__

DEV float b2f(u16 v) { unsigned u = ((unsigned)v) << 16; return __builtin_bit_cast(float, u); }
DEV u16 f2bf(float f) {
  unsigned u = __builtin_bit_cast(unsigned, f);
  u += 0x7fffu + ((u >> 16) & 1u);
  return (u16)(u >> 16);
}

DEV void async16(const void* g, void* l) {
  __builtin_amdgcn_global_load_lds(
      (const __attribute__((address_space(1))) void*)g,
      (__attribute__((address_space(3))) void*)l, 16, 0, 0);
}

// ---------------------------------------------------------------------------
// f32 -> bf16 conversion
// ---------------------------------------------------------------------------
__global__ __launch_bounds__(256) void cvt_kernel(
    const float* __restrict__ in, u16* __restrict__ out, int n4)
{
  const int i = blockIdx.x * 256 + threadIdx.x;
  if (i < n4) {
    float4 v = ((const float4*)in)[i];
    u16x4 o;
    o[0] = f2bf(v.x); o[1] = f2bf(v.y); o[2] = f2bf(v.z); o[3] = f2bf(v.w);
    ((u16x4*)out)[i] = o;
  }
}

// ---------------------------------------------------------------------------
// CPB bias table, TRANSPOSED: btblT[h][j][i] = 16*sigmoid(tbl[i-j+63][h])
// ---------------------------------------------------------------------------
__global__ __launch_bounds__(64) void cpb_kernel(
    const float* __restrict__ w1, const float* __restrict__ b1,
    const float* __restrict__ w2, float* __restrict__ btbl)
{
  const int h = blockIdx.x;
  const int lane = threadIdx.x;
  __shared__ float tbl[127];
  for (int r = lane; r < 127; r += 64) {
    float rv = (float)(r - 63) * (8.0f / 63.0f);
    float sgn = (rv > 0.f) ? 1.f : ((rv < 0.f) ? -1.f : 0.f);
    float t = sgn * log2f(fabsf(rv) + 1.f) * (1.f / 3.f);
    float acc = 0.f;
    for (int k = 0; k < 512; ++k) {
      float hid = fmaxf(t * w1[k] + b1[k], 0.f);
      acc += hid * w2[h * 512 + k];
    }
    tbl[r] = acc;
  }
  __syncthreads();
  for (int idx = lane; idx < 4096; idx += 64) {
    int j = idx >> 6, i = idx & 63;               // transposed: [j][i]
    float v = tbl[i - j + 63];
    btbl[h * 4096 + idx] = 16.f / (1.f + __expf(-v));
  }
}

// ---------------------------------------------------------------------------
// GEMM  C[m][n] = sum_k A[m][k] * W[n][k]
// MODE 0: qkv (roll folded; A rows local to half; scatter + q/v bias)
// MODE 1: proj (A = attnT layout [16][32768][32]; +bias)
// MODE 2: fc1 (+bias+gelu)   MODE 3: fc2 (+bias)
// ---------------------------------------------------------------------------
template <int MODE>
__global__ __launch_bounds__(256) void gemm_bt(
    const u16* __restrict__ A, const u16* __restrict__ W,
    const float* __restrict__ bias1, const float* __restrict__ bias2,
    u16* __restrict__ out, int M, int N, int K, int m_base)
{
  constexpr int BK = 32;
  __shared__ __attribute__((aligned(16))) u16 lA[128 * BK];
  __shared__ __attribute__((aligned(16))) u16 lB[128 * BK];
  const int tid = threadIdx.x;
  const int wid = tid >> 6;
  const int lane = tid & 63;
  const int m0 = blockIdx.x * 128;
  const int n0 = blockIdx.y * 128;
  const int wm = (wid >> 1) * 64;
  const int wn = (wid & 1) * 64;
  f32x4 acc[4][4] = {};

  const int srow = lane >> 2;
  const int scol = (lane & 3) * 8;

  for (int k0 = 0; k0 < K; k0 += BK) {
    #pragma unroll
    for (int cc = 0; cc < 2; ++cc) {
      const int chunk = wid * 2 + cc;
      const int r = chunk * 16 + srow;
      const u16* asrc;
      if constexpr (MODE == 0) {
        const int mg = m_base + m0 + r;
        const int bb = mg >> 12;
        const int p = mg & 4095;
        const long ga = (((long)bb << 12) + ((p + 32) & 4095)) - m_base;
        asrc = A + ga * (long)K + k0 + scol;
      } else if constexpr (MODE == 1) {
        // A layout [16][32768][32]: h = k>>5, d = k&31
        asrc = A + (size_t)(k0 >> 5) * 1048576 + (size_t)(m0 + r) * 32 + scol;
      } else {
        asrc = A + (long)(m0 + r) * K + k0 + scol;
      }
      async16(asrc, &lA[chunk * 512]);
      async16(W + (long)(n0 + r) * K + k0 + scol, &lB[chunk * 512]);
    }
    __syncthreads();
    const int frow = lane & 15;
    const int fk = (lane >> 4) * 8;
    bf16x8 fa[4], fb[4];
    #pragma unroll
    for (int t = 0; t < 4; ++t) {
      fa[t] = *(const bf16x8*)&lA[(wm + t * 16 + frow) * BK + fk];
      fb[t] = *(const bf16x8*)&lB[(wn + t * 16 + frow) * BK + fk];
    }
    #pragma unroll
    for (int mi = 0; mi < 4; ++mi)
      #pragma unroll
      for (int ni = 0; ni < 4; ++ni)
        acc[mi][ni] = __builtin_amdgcn_mfma_f32_16x16x32_bf16(fa[mi], fb[ni], acc[mi][ni], 0, 0, 0);
    __syncthreads();
  }

  const int lrow = (lane >> 4) * 4;
  const int lcol = lane & 15;
  #pragma unroll
  for (int mi = 0; mi < 4; ++mi) {
    #pragma unroll
    for (int ni = 0; ni < 4; ++ni) {
      const int n = n0 + wn + ni * 16 + lcol;
      #pragma unroll
      for (int r = 0; r < 4; ++r) {
        const int m = m0 + wm + mi * 16 + lrow + r;
        float v = acc[mi][ni][r];
        if constexpr (MODE == 0) {
          const int which = n >> 9, c = n & 511;
          const int hh = c >> 5, d = c & 31;
          float bias = (which == 0) ? bias1[c] : (which == 2 ? bias2[c] : 0.f);
          const int g = m >> 6, ii = m & 63;
          out[(size_t)which * 8388608 + (size_t)g * 32768 + hh * 2048 + ii * 32 + d] =
              f2bf(v + bias);
        } else if constexpr (MODE == 2) {
          float t = v + bias1[n];
          float ge = 0.5f * t * (1.f + erff(t * 0.70710678118654752f));
          out[(size_t)m * N + n] = f2bf(ge);
        } else {
          out[(size_t)m * N + n] = f2bf(v + bias1[n]);
        }
      }
    }
  }
}

// ---------------------------------------------------------------------------
// Attention v2: 512 blocks (one per window), 4 waves/block, wave = 4 heads,
// thread = query row. K/V staged f32 in LDS (XOR-swizzled float4 units).
// Fixed-max softmax (m = scale+16). Output transposed: attnT[h][row][32].
// ---------------------------------------------------------------------------
__global__ __launch_bounds__(256) void attn_kernel(
    const u16* __restrict__ qkv0, const u16* __restrict__ qkv1,
    const float* __restrict__ ls, const float* __restrict__ btblT,
    u16* __restrict__ attnT)
{
  const int gg = blockIdx.x;                       // global window 0..511
  const u16* qkv = (gg < 256) ? qkv0 : qkv1;
  const int g = gg & 255;
  const int w = threadIdx.x >> 6;
  const int lane = threadIdx.x & 63;
  __shared__ float kf[4][64][32];
  __shared__ float vf[4][64][32];
  __shared__ float kinv[4][64];
  const bool maskw = ((gg & 63) == 63);
  const bool ileft = lane < 32;

  for (int t = 0; t < 4; ++t) {
    const int h = w * 4 + t;
    const size_t bgh = (size_t)g * 32768 + (size_t)h * 2048;

    // ---- stage K,V (lane = row), compute kinv ----
    {
      const u16x8* kp = (const u16x8*)(qkv + 8388608 + bgh + (size_t)lane * 32);
      const u16x8* vp = (const u16x8*)(qkv + 16777216 + bgh + (size_t)lane * 32);
      float4* krow = (float4*)&kf[w][lane][0];
      float4* vrow = (float4*)&vf[w][lane][0];
      const int sw = lane & 7;
      float ks = 0.f;
      #pragma unroll
      for (int c = 0; c < 4; ++c) {
        u16x8 kr = kp[c];
        float4 lo, hi;
        lo.x = b2f(kr[0]); lo.y = b2f(kr[1]); lo.z = b2f(kr[2]); lo.w = b2f(kr[3]);
        hi.x = b2f(kr[4]); hi.y = b2f(kr[5]); hi.z = b2f(kr[6]); hi.w = b2f(kr[7]);
        ks += lo.x*lo.x + lo.y*lo.y + lo.z*lo.z + lo.w*lo.w
            + hi.x*hi.x + hi.y*hi.y + hi.z*hi.z + hi.w*hi.w;
        krow[(2*c) ^ sw] = lo;
        krow[(2*c+1) ^ sw] = hi;
        u16x8 vr = vp[c];
        float4 vlo, vhi;
        vlo.x = b2f(vr[0]); vlo.y = b2f(vr[1]); vlo.z = b2f(vr[2]); vlo.w = b2f(vr[3]);
        vhi.x = b2f(vr[4]); vhi.y = b2f(vr[5]); vhi.z = b2f(vr[6]); vhi.w = b2f(vr[7]);
        vrow[(2*c) ^ sw] = vlo;
        vrow[(2*c+1) ^ sw] = vhi;
      }
      kinv[w][lane] = 1.f / fmaxf(sqrtf(ks), 1e-12f);
    }
    __syncthreads();

    // ---- load Q row ----
    float q[32];
    float qs = 0.f;
    {
      const u16x8* qp = (const u16x8*)(qkv + bgh + (size_t)lane * 32);
      #pragma unroll
      for (int c = 0; c < 4; ++c) {
        u16x8 r = qp[c];
        #pragma unroll
        for (int e = 0; e < 8; ++e) { float f = b2f(r[e]); q[c * 8 + e] = f; qs += f * f; }
      }
    }
    const float scale = __expf(fminf(ls[h], 4.6051701859880914f));
    const float qmul = (1.f / fmaxf(sqrtf(qs), 1e-12f)) * scale;
    const float mh = scale + 16.f;
    const float* bt = btblT + h * 4096 + lane;

    float l = 0.f;
    float o[32];
    #pragma unroll
    for (int d = 0; d < 32; ++d) o[d] = 0.f;

    #pragma unroll 4
    for (int j = 0; j < 64; ++j) {
      const float4* kr = (const float4*)&kf[w][j][0];
      const float4* vr = (const float4*)&vf[w][j][0];
      const int sw = j & 7;
      float p0 = 0.f, p1 = 0.f, p2 = 0.f, p3 = 0.f;
      #pragma unroll
      for (int u = 0; u < 8; u += 4) {
        float4 a0 = kr[(u + 0) ^ sw], a1 = kr[(u + 1) ^ sw];
        float4 a2 = kr[(u + 2) ^ sw], a3 = kr[(u + 3) ^ sw];
        p0 += q[u*4+ 0]*a0.x + q[u*4+ 1]*a0.y + q[u*4+ 2]*a0.z + q[u*4+ 3]*a0.w;
        p1 += q[u*4+ 4]*a1.x + q[u*4+ 5]*a1.y + q[u*4+ 6]*a1.z + q[u*4+ 7]*a1.w;
        p2 += q[u*4+ 8]*a2.x + q[u*4+ 9]*a2.y + q[u*4+10]*a2.z + q[u*4+11]*a2.w;
        p3 += q[u*4+12]*a3.x + q[u*4+13]*a3.y + q[u*4+14]*a3.z + q[u*4+15]*a3.w;
      }
      float s = ((p0 + p1) + (p2 + p3)) * (kinv[w][j] * qmul) + bt[j * 64];
      if (maskw && (ileft != (j < 32))) s -= 100.f;
      float e = __expf(s - mh);
      l += e;
      #pragma unroll
      for (int u = 0; u < 8; ++u) {
        float4 b = vr[u ^ sw];
        o[u*4+0] += e*b.x; o[u*4+1] += e*b.y; o[u*4+2] += e*b.z; o[u*4+3] += e*b.w;
      }
    }

    const float inv = 1.f / fmaxf(l, 1e-37f);
    u16* op = attnT + (size_t)h * 1048576 + (size_t)(gg * 64 + lane) * 32;
    #pragma unroll
    for (int c = 0; c < 4; ++c) {
      u16x8 r;
      #pragma unroll
      for (int e = 0; e < 8; ++e) r[e] = f2bf(o[c * 8 + e] * inv);
      *(u16x8*)(op + c * 8) = r;
    }
    __syncthreads();
  }
}

// ---------------------------------------------------------------------------
// LN1: x1h = bf16( x + LN(roll_back(proj_out)) ),  x read as f32
// ---------------------------------------------------------------------------
__global__ __launch_bounds__(256) void ln1_kernel(
    const u16* __restrict__ proj, const float* __restrict__ x,
    const float* __restrict__ w, const float* __restrict__ bb,
    u16* __restrict__ x1h)
{
  const int t = blockIdx.x;
  const int b = t >> 12, l = t & 4095;
  const int p = (l - 32) & 4095;
  const size_t srow = (((size_t)b << 12) + p) << 9;
  const int c0 = threadIdx.x * 2;
  u16x2 pv = *(const u16x2*)(proj + srow + c0);
  float v0 = b2f(pv[0]), v1 = b2f(pv[1]);
  float s = v0 + v1, ss = v0 * v0 + v1 * v1;
  #pragma unroll
  for (int o = 32; o > 0; o >>= 1) { s += __shfl_down(s, o); ss += __shfl_down(ss, o); }
  __shared__ float red[8];
  const int wid = threadIdx.x >> 6, lane = threadIdx.x & 63;
  if (lane == 0) { red[wid] = s; red[4 + wid] = ss; }
  __syncthreads();
  const float S = red[0] + red[1] + red[2] + red[3];
  const float SS = red[4] + red[5] + red[6] + red[7];
  const float mean = S * (1.f / 512.f);
  const float var = SS * (1.f / 512.f) - mean * mean;
  const float rstd = rsqrtf(var + 1e-5f);
  const size_t orow = (size_t)t << 9;
  float2 xv = *(const float2*)(x + orow + c0);
  const float r0 = xv.x + (v0 - mean) * rstd * w[c0] + bb[c0];
  const float r1 = xv.y + (v1 - mean) * rstd * w[c0 + 1] + bb[c0 + 1];
  u16x2 ho; ho[0] = f2bf(r0); ho[1] = f2bf(r1);
  *(u16x2*)(x1h + orow + c0) = ho;
}

// ---------------------------------------------------------------------------
// LN2 (per half, local rows): out = f32( x1 + LN(fc2_out) )
// ---------------------------------------------------------------------------
__global__ __launch_bounds__(256) void ln2_kernel(
    const u16* __restrict__ fc2, const u16* __restrict__ x1h,
    const float* __restrict__ w, const float* __restrict__ bb,
    float* __restrict__ out)
{
  const int t = blockIdx.x;
  const size_t row = (size_t)t << 9;
  const int c0 = threadIdx.x * 2;
  u16x2 pv = *(const u16x2*)(fc2 + row + c0);
  float v0 = b2f(pv[0]), v1 = b2f(pv[1]);
  float s = v0 + v1, ss = v0 * v0 + v1 * v1;
  #pragma unroll
  for (int o = 32; o > 0; o >>= 1) { s += __shfl_down(s, o); ss += __shfl_down(ss, o); }
  __shared__ float red[8];
  const int wid = threadIdx.x >> 6, lane = threadIdx.x & 63;
  if (lane == 0) { red[wid] = s; red[4 + wid] = ss; }
  __syncthreads();
  const float S = red[0] + red[1] + red[2] + red[3];
  const float SS = red[4] + red[5] + red[6] + red[7];
  const float mean = S * (1.f / 512.f);
  const float var = SS * (1.f / 512.f) - mean * mean;
  const float rstd = rsqrtf(var + 1e-5f);
  u16x2 xv = *(const u16x2*)(x1h + row + c0);
  const float r0 = b2f(xv[0]) + (v0 - mean) * rstd * w[c0] + bb[c0];
  const float r1 = b2f(xv[1]) + (v1 - mean) * rstd * w[c0 + 1] + bb[c0 + 1];
  float2 fo; fo.x = r0; fo.y = r1;
  *(float2*)(out + row + c0) = fo;
}

// ---------------------------------------------------------------------------
extern "C" void kernel_launch(void* const* d_in, const int* in_sizes, int n_in,
                              void* d_out, int out_size, void* d_ws, size_t ws_size,
                              hipStream_t stream) {
  const float* x        = (const float*)d_in[0];
  const float* qkv_w    = (const float*)d_in[1];
  const float* q_bias   = (const float*)d_in[2];
  const float* v_bias   = (const float*)d_in[3];
  const float* lscale   = (const float*)d_in[4];
  const float* cpb_w1   = (const float*)d_in[5];
  const float* cpb_b1   = (const float*)d_in[6];
  const float* cpb_w2   = (const float*)d_in[7];
  const float* proj_w   = (const float*)d_in[8];
  const float* proj_b   = (const float*)d_in[9];
  const float* n1w      = (const float*)d_in[10];
  const float* n1b      = (const float*)d_in[11];
  const float* n2w      = (const float*)d_in[12];
  const float* n2b      = (const float*)d_in[13];
  const float* fc1_w    = (const float*)d_in[14];
  const float* fc1_b    = (const float*)d_in[15];
  const float* fc2_w    = (const float*)d_in[16];
  const float* fc2_b    = (const float*)d_in[17];

  if (ws_size < 134217728u) return;
  char* ws = (char*)d_ws;
  // weights [0, 6291456)
  u16* wqkv  = (u16*)(ws + 0);
  u16* wproj = (u16*)(ws + 1572864);
  u16* wfc1  = (u16*)(ws + 2097152);
  u16* wfc2  = (u16*)(ws + 4194304);
  u16* qkvh0 = (u16*)(ws + 6291456);    // 50,331,648 B  -> end 56,623,104
  u16* qkvh1 = (u16*)(ws + 56623104);   // 50,331,648 B  -> end 106,954,752
  u16* xbf   = (u16*)(ws + 106954752);  // 16,777,216 B per half -> end 123,731,968
  u16* x1h   = (u16*)(ws + 6291456);    // 33,554,432 B  (qkv dead at ln1)
  u16* projo = (u16*)(ws + 39845888);   // 33,554,432 B  (proj-gemm -> ln1)
  u16* hbuf  = (u16*)(ws + 39845888);   // 67,108,864 B per half (projo/qkvh1 dead)
  u16* fc2oh = (u16*)(ws + 107003904);  // 16,777,216 B per half (xbf dead)
  // d_out scratch (67,108,864 B total): attnT [0,33554432), btblT at 33554432
  u16* attnT  = (u16*)d_out;
  float* btbl = (float*)((char*)d_out + 33554432);
  float* out  = (float*)d_out;

  cpb_kernel<<<16, 64, 0, stream>>>(cpb_w1, cpb_b1, cpb_w2, btbl);
  cvt_kernel<<<768, 256, 0, stream>>>(qkv_w, wqkv, 196608);
  cvt_kernel<<<256, 256, 0, stream>>>(proj_w, wproj, 65536);
  cvt_kernel<<<1024, 256, 0, stream>>>(fc1_w, wfc1, 262144);
  cvt_kernel<<<1024, 256, 0, stream>>>(fc2_w, wfc2, 262144);

  for (int half = 0; half < 2; ++half) {
    cvt_kernel<<<8192, 256, 0, stream>>>(x + (size_t)half * 8388608, xbf, 2097152);
    gemm_bt<0><<<dim3(128, 12), 256, 0, stream>>>(
        xbf, wqkv, q_bias, v_bias, half ? qkvh1 : qkvh0,
        16384, 1536, 512, half * 16384);
  }
  attn_kernel<<<512, 256, 0, stream>>>(qkvh0, qkvh1, lscale, btbl, attnT);
  gemm_bt<1><<<dim3(256, 4), 256, 0, stream>>>(
      attnT, wproj, proj_b, nullptr, projo, 32768, 512, 512, 0);
  ln1_kernel<<<32768, 256, 0, stream>>>(projo, x, n1w, n1b, x1h);
  for (int half = 0; half < 2; ++half) {
    const u16* a2 = x1h + (size_t)half * 8388608;
    gemm_bt<2><<<dim3(128, 16), 256, 0, stream>>>(
        a2, wfc1, fc1_b, nullptr, hbuf, 16384, 2048, 512, 0);
    gemm_bt<3><<<dim3(128, 4), 256, 0, stream>>>(
        hbuf, wfc2, fc2_b, nullptr, fc2oh, 16384, 512, 2048, 0);
    ln2_kernel<<<16384, 256, 0, stream>>>(
        fc2oh, a2, n2w, n2b, out + (size_t)half * 8388608);
  }
}

// Round 5
// 550.270 us; speedup vs baseline: 1.6225x; 1.2373x over previous
//
#include <hip/hip_runtime.h>
#include <hip/hip_bf16.h>
#include <math.h>

typedef unsigned short u16;
typedef __bf16 bf16x8 __attribute__((ext_vector_type(8)));
typedef float f32x4 __attribute__((ext_vector_type(4)));
typedef unsigned short u16x8 __attribute__((ext_vector_type(8)));
typedef unsigned short u16x4 __attribute__((ext_vector_type(4)));
typedef unsigned short u16x2 __attribute__((ext_vector_type(2)));

#define DEV static __device__ __forceinline__

DEV float b2f(u16 v) { unsigned u = ((unsigned)v) << 16; return __builtin_bit_cast(float, u); }
DEV u16 f2bf(float f) {
  unsigned u = __builtin_bit_cast(unsigned, f);
  u += 0x7fffu + ((u >> 16) & 1u);
  return (u16)(u >> 16);
}

DEV void async16(const void* g, void* l) {
  __builtin_amdgcn_global_load_lds(
      (const __attribute__((address_space(1))) void*)g,
      (__attribute__((address_space(3))) void*)l, 16, 0, 0);
}

// ---------------------------------------------------------------------------
// f32 -> bf16 conversion
// ---------------------------------------------------------------------------
__global__ __launch_bounds__(256) void cvt_kernel(
    const float* __restrict__ in, u16* __restrict__ out, int n4)
{
  const int i = blockIdx.x * 256 + threadIdx.x;
  if (i < n4) {
    float4 v = ((const float4*)in)[i];
    u16x4 o;
    o[0] = f2bf(v.x); o[1] = f2bf(v.y); o[2] = f2bf(v.z); o[3] = f2bf(v.w);
    ((u16x4*)out)[i] = o;
  }
}

// ---------------------------------------------------------------------------
// CPB bias table: btbl[h][i][j] = 16*sigmoid(tbl[i-j+63][h])   (row-major i,j)
// ---------------------------------------------------------------------------
__global__ __launch_bounds__(64) void cpb_kernel(
    const float* __restrict__ w1, const float* __restrict__ b1,
    const float* __restrict__ w2, float* __restrict__ btbl)
{
  const int h = blockIdx.x;
  const int lane = threadIdx.x;
  __shared__ float tbl[127];
  for (int r = lane; r < 127; r += 64) {
    float rv = (float)(r - 63) * (8.0f / 63.0f);
    float sgn = (rv > 0.f) ? 1.f : ((rv < 0.f) ? -1.f : 0.f);
    float t = sgn * log2f(fabsf(rv) + 1.f) * (1.f / 3.f);
    float acc = 0.f;
    for (int k = 0; k < 512; ++k) {
      float hid = fmaxf(t * w1[k] + b1[k], 0.f);
      acc += hid * w2[h * 512 + k];
    }
    tbl[r] = acc;
  }
  __syncthreads();
  for (int idx = lane; idx < 4096; idx += 64) {
    int i = idx >> 6, j = idx & 63;
    float v = tbl[i - j + 63];
    btbl[h * 4096 + idx] = 16.f / (1.f + __expf(-v));
  }
}

// ---------------------------------------------------------------------------
// GEMM  C[m][n] = sum_k A[m][k] * W[n][k]
// MODE 0: qkv (roll folded; A rows local to half; scatter + q/v bias)
// MODE 1: proj (A = attnT layout [16][32768][32]; +bias)
// MODE 2: fc1 (+bias+gelu)   MODE 3: fc2 (+bias)
// ---------------------------------------------------------------------------
template <int MODE>
__global__ __launch_bounds__(256) void gemm_bt(
    const u16* __restrict__ A, const u16* __restrict__ W,
    const float* __restrict__ bias1, const float* __restrict__ bias2,
    u16* __restrict__ out, int M, int N, int K, int m_base)
{
  constexpr int BK = 32;
  __shared__ __attribute__((aligned(16))) u16 lA[128 * BK];
  __shared__ __attribute__((aligned(16))) u16 lB[128 * BK];
  const int tid = threadIdx.x;
  const int wid = tid >> 6;
  const int lane = tid & 63;
  const int m0 = blockIdx.x * 128;
  const int n0 = blockIdx.y * 128;
  const int wm = (wid >> 1) * 64;
  const int wn = (wid & 1) * 64;
  f32x4 acc[4][4] = {};

  const int srow = lane >> 2;
  const int scol = (lane & 3) * 8;

  for (int k0 = 0; k0 < K; k0 += BK) {
    #pragma unroll
    for (int cc = 0; cc < 2; ++cc) {
      const int chunk = wid * 2 + cc;
      const int r = chunk * 16 + srow;
      const u16* asrc;
      if constexpr (MODE == 0) {
        const int mg = m_base + m0 + r;
        const int bb = mg >> 12;
        const int p = mg & 4095;
        const long ga = (((long)bb << 12) + ((p + 32) & 4095)) - m_base;
        asrc = A + ga * (long)K + k0 + scol;
      } else if constexpr (MODE == 1) {
        asrc = A + (size_t)(k0 >> 5) * 1048576 + (size_t)(m0 + r) * 32 + scol;
      } else {
        asrc = A + (long)(m0 + r) * K + k0 + scol;
      }
      async16(asrc, &lA[chunk * 512]);
      async16(W + (long)(n0 + r) * K + k0 + scol, &lB[chunk * 512]);
    }
    __syncthreads();
    const int frow = lane & 15;
    const int fk = (lane >> 4) * 8;
    bf16x8 fa[4], fb[4];
    #pragma unroll
    for (int t = 0; t < 4; ++t) {
      fa[t] = *(const bf16x8*)&lA[(wm + t * 16 + frow) * BK + fk];
      fb[t] = *(const bf16x8*)&lB[(wn + t * 16 + frow) * BK + fk];
    }
    #pragma unroll
    for (int mi = 0; mi < 4; ++mi)
      #pragma unroll
      for (int ni = 0; ni < 4; ++ni)
        acc[mi][ni] = __builtin_amdgcn_mfma_f32_16x16x32_bf16(fa[mi], fb[ni], acc[mi][ni], 0, 0, 0);
    __syncthreads();
  }

  const int lrow = (lane >> 4) * 4;
  const int lcol = lane & 15;
  #pragma unroll
  for (int mi = 0; mi < 4; ++mi) {
    #pragma unroll
    for (int ni = 0; ni < 4; ++ni) {
      const int n = n0 + wn + ni * 16 + lcol;
      #pragma unroll
      for (int r = 0; r < 4; ++r) {
        const int m = m0 + wm + mi * 16 + lrow + r;
        float v = acc[mi][ni][r];
        if constexpr (MODE == 0) {
          const int which = n >> 9, c = n & 511;
          const int hh = c >> 5, d = c & 31;
          float bias = (which == 0) ? bias1[c] : (which == 2 ? bias2[c] : 0.f);
          const int g = m >> 6, ii = m & 63;
          out[(size_t)which * 8388608 + (size_t)g * 32768 + hh * 2048 + ii * 32 + d] =
              f2bf(v + bias);
        } else if constexpr (MODE == 2) {
          float t = v + bias1[n];
          float ge = 0.5f * t * (1.f + erff(t * 0.70710678118654752f));
          out[(size_t)m * N + n] = f2bf(ge);
        } else {
          out[(size_t)m * N + n] = f2bf(v + bias1[n]);
        }
      }
    }
  }
}

// ---------------------------------------------------------------------------
// Attention v3 (MFMA): 512 blocks x 4 waves; wave = (window gg, heads w*4+t).
// Q/K fragments straight from global (frag layout row=lane&15, k=(lane>>4)*8),
// row norms via shfl_xor(16/32). S = 16 mfma_16x16x32. Fixed-max softmax in
// C-layout regs, rowsum via shfl_xor(1/2/4/8). P and V^T staged in XOR-
// swizzled LDS -> 16 mfma PV. O scaled by 1/rowsum at write.
// ---------------------------------------------------------------------------
__global__ __launch_bounds__(256) void attn_kernel(
    const u16* __restrict__ qkv0, const u16* __restrict__ qkv1,
    const float* __restrict__ ls, const float* __restrict__ btbl,
    u16* __restrict__ attnT)
{
  const int gg = blockIdx.x;
  const u16* qkv = (gg < 256) ? qkv0 : qkv1;
  const int g = gg & 255;
  const int w = threadIdx.x >> 6;
  const int lane = threadIdx.x & 63;
  __shared__ __attribute__((aligned(16))) u16 vt[4][2048];   // V^T [32][64] swizzled
  __shared__ __attribute__((aligned(16))) u16 pl[4][4096];   // P [64][64] swizzled
  const bool maskw = ((gg & 63) == 63);
  const int fr = lane & 15;            // frag row / C col
  const int fkq = (lane >> 4) * 8;     // frag k-piece
  const int crow = (lane >> 4) * 4;    // C row base

  for (int t = 0; t < 4; ++t) {
    const int h = w * 4 + t;
    const size_t bgh = (size_t)g * 32768 + (size_t)h * 2048;

    // ---- stage V^T (lane = row j of V, writes column j of VT) ----
    {
      const u16x8* vp = (const u16x8*)(qkv + 16777216 + bgh + (size_t)lane * 32);
      #pragma unroll
      for (int c = 0; c < 4; ++c) {
        u16x8 vr = vp[c];
        #pragma unroll
        for (int e = 0; e < 8; ++e) {
          const int d = c * 8 + e;
          const int addr = d * 64 + (((lane >> 3) ^ (d & 7)) << 3) + (lane & 7);
          vt[w][addr] = vr[e];
        }
      }
    }

    // ---- Q/K fragments + per-row norms (scale folded into Q) ----
    const float scale = __expf(fminf(ls[h], 4.6051701859880914f));
    bf16x8 qa[4], kb[4];
    #pragma unroll
    for (int mi = 0; mi < 4; ++mi) {
      u16x8 raw = *(const u16x8*)(qkv + bgh + (size_t)(mi * 16 + fr) * 32 + fkq);
      float f[8]; float ssum = 0.f;
      #pragma unroll
      for (int e = 0; e < 8; ++e) { f[e] = b2f(raw[e]); ssum += f[e] * f[e]; }
      ssum += __shfl_xor(ssum, 16); ssum += __shfl_xor(ssum, 32);
      const float mul = scale / fmaxf(sqrtf(ssum), 1e-12f);
      u16x8 tmp;
      #pragma unroll
      for (int e = 0; e < 8; ++e) tmp[e] = f2bf(f[e] * mul);
      qa[mi] = __builtin_bit_cast(bf16x8, tmp);
    }
    #pragma unroll
    for (int ni = 0; ni < 4; ++ni) {
      u16x8 raw = *(const u16x8*)(qkv + 8388608 + bgh + (size_t)(ni * 16 + fr) * 32 + fkq);
      float f[8]; float ssum = 0.f;
      #pragma unroll
      for (int e = 0; e < 8; ++e) { f[e] = b2f(raw[e]); ssum += f[e] * f[e]; }
      ssum += __shfl_xor(ssum, 16); ssum += __shfl_xor(ssum, 32);
      const float mul = 1.f / fmaxf(sqrtf(ssum), 1e-12f);
      u16x8 tmp;
      #pragma unroll
      for (int e = 0; e < 8; ++e) tmp[e] = f2bf(f[e] * mul);
      kb[ni] = __builtin_bit_cast(bf16x8, tmp);
    }

    // ---- S = qn kn^T : 16 MFMAs ----
    f32x4 s[4][4] = {};
    #pragma unroll
    for (int mi = 0; mi < 4; ++mi)
      #pragma unroll
      for (int ni = 0; ni < 4; ++ni)
        s[mi][ni] = __builtin_amdgcn_mfma_f32_16x16x32_bf16(qa[mi], kb[ni], s[mi][ni], 0, 0, 0);

    // ---- bias + mask + exp (fixed max) + row sums ----
    const float mh = scale + 16.f;
    float inv_[4][4];
    #pragma unroll
    for (int mi = 0; mi < 4; ++mi) {
      #pragma unroll
      for (int r = 0; r < 4; ++r) {
        const int row = mi * 16 + crow + r;
        float es = 0.f;
        #pragma unroll
        for (int ni = 0; ni < 4; ++ni) {
          const int col = ni * 16 + fr;
          float sv = s[mi][ni][r] + btbl[h * 4096 + row * 64 + col];
          if (maskw && ((row < 32) != (col < 32))) sv -= 100.f;
          const float e = __expf(sv - mh);
          s[mi][ni][r] = e;
          es += e;
        }
        es += __shfl_xor(es, 1); es += __shfl_xor(es, 2);
        es += __shfl_xor(es, 4); es += __shfl_xor(es, 8);
        inv_[mi][r] = 1.f / fmaxf(es, 1e-37f);
      }
    }

    // ---- P -> LDS (bf16, swizzled) ----
    #pragma unroll
    for (int mi = 0; mi < 4; ++mi)
      #pragma unroll
      for (int r = 0; r < 4; ++r) {
        const int row = mi * 16 + crow + r;
        #pragma unroll
        for (int ni = 0; ni < 4; ++ni) {
          const int col = ni * 16 + fr;
          const int addr = row * 64 + (((col >> 3) ^ (row & 7)) << 3) + (col & 7);
          pl[w][addr] = f2bf(s[mi][ni][r]);
        }
      }
    __syncthreads();

    // ---- O = P V : 16 MFMAs ----
    f32x4 o[4][2] = {};
    #pragma unroll
    for (int ks = 0; ks < 2; ++ks) {
      bf16x8 vbf[2];
      #pragma unroll
      for (int np = 0; np < 2; ++np) {
        const int d = np * 16 + fr;
        const int jb = (lane >> 4) + ks * 4;
        vbf[np] = *(const bf16x8*)&vt[w][d * 64 + ((jb ^ (d & 7)) << 3)];
      }
      #pragma unroll
      for (int mp = 0; mp < 4; ++mp) {
        const int row = mp * 16 + fr;
        const int cb = (lane >> 4) + ks * 4;
        bf16x8 paf = *(const bf16x8*)&pl[w][row * 64 + ((cb ^ (row & 7)) << 3)];
        o[mp][0] = __builtin_amdgcn_mfma_f32_16x16x32_bf16(paf, vbf[0], o[mp][0], 0, 0, 0);
        o[mp][1] = __builtin_amdgcn_mfma_f32_16x16x32_bf16(paf, vbf[1], o[mp][1], 0, 0, 0);
      }
    }

    // ---- write O (normalized) to attnT[h][gg*64+row][d] ----
    #pragma unroll
    for (int mp = 0; mp < 4; ++mp)
      #pragma unroll
      for (int r = 0; r < 4; ++r) {
        const int row = mp * 16 + crow + r;
        const float iv = inv_[mp][r];
        u16* op = attnT + (size_t)h * 1048576 + (size_t)(gg * 64 + row) * 32;
        op[fr]      = f2bf(o[mp][0][r] * iv);
        op[16 + fr] = f2bf(o[mp][1][r] * iv);
      }
    __syncthreads();
  }
}

// ---------------------------------------------------------------------------
// LN1: x1h = bf16( x + LN(roll_back(proj_out)) ),  x read as f32
// ---------------------------------------------------------------------------
__global__ __launch_bounds__(256) void ln1_kernel(
    const u16* __restrict__ proj, const float* __restrict__ x,
    const float* __restrict__ w, const float* __restrict__ bb,
    u16* __restrict__ x1h)
{
  const int t = blockIdx.x;
  const int b = t >> 12, l = t & 4095;
  const int p = (l - 32) & 4095;
  const size_t srow = (((size_t)b << 12) + p) << 9;
  const int c0 = threadIdx.x * 2;
  u16x2 pv = *(const u16x2*)(proj + srow + c0);
  float v0 = b2f(pv[0]), v1 = b2f(pv[1]);
  float s = v0 + v1, ss = v0 * v0 + v1 * v1;
  #pragma unroll
  for (int o = 32; o > 0; o >>= 1) { s += __shfl_down(s, o); ss += __shfl_down(ss, o); }
  __shared__ float red[8];
  const int wid = threadIdx.x >> 6, lane = threadIdx.x & 63;
  if (lane == 0) { red[wid] = s; red[4 + wid] = ss; }
  __syncthreads();
  const float S = red[0] + red[1] + red[2] + red[3];
  const float SS = red[4] + red[5] + red[6] + red[7];
  const float mean = S * (1.f / 512.f);
  const float var = SS * (1.f / 512.f) - mean * mean;
  const float rstd = rsqrtf(var + 1e-5f);
  const size_t orow = (size_t)t << 9;
  float2 xv = *(const float2*)(x + orow + c0);
  const float r0 = xv.x + (v0 - mean) * rstd * w[c0] + bb[c0];
  const float r1 = xv.y + (v1 - mean) * rstd * w[c0 + 1] + bb[c0 + 1];
  u16x2 ho; ho[0] = f2bf(r0); ho[1] = f2bf(r1);
  *(u16x2*)(x1h + orow + c0) = ho;
}

// ---------------------------------------------------------------------------
// LN2 (per half, local rows): out = f32( x1 + LN(fc2_out) )
// ---------------------------------------------------------------------------
__global__ __launch_bounds__(256) void ln2_kernel(
    const u16* __restrict__ fc2, const u16* __restrict__ x1h,
    const float* __restrict__ w, const float* __restrict__ bb,
    float* __restrict__ out)
{
  const int t = blockIdx.x;
  const size_t row = (size_t)t << 9;
  const int c0 = threadIdx.x * 2;
  u16x2 pv = *(const u16x2*)(fc2 + row + c0);
  float v0 = b2f(pv[0]), v1 = b2f(pv[1]);
  float s = v0 + v1, ss = v0 * v0 + v1 * v1;
  #pragma unroll
  for (int o = 32; o > 0; o >>= 1) { s += __shfl_down(s, o); ss += __shfl_down(ss, o); }
  __shared__ float red[8];
  const int wid = threadIdx.x >> 6, lane = threadIdx.x & 63;
  if (lane == 0) { red[wid] = s; red[4 + wid] = ss; }
  __syncthreads();
  const float S = red[0] + red[1] + red[2] + red[3];
  const float SS = red[4] + red[5] + red[6] + red[7];
  const float mean = S * (1.f / 512.f);
  const float var = SS * (1.f / 512.f) - mean * mean;
  const float rstd = rsqrtf(var + 1e-5f);
  u16x2 xv = *(const u16x2*)(x1h + row + c0);
  const float r0 = b2f(xv[0]) + (v0 - mean) * rstd * w[c0] + bb[c0];
  const float r1 = b2f(xv[1]) + (v1 - mean) * rstd * w[c0 + 1] + bb[c0 + 1];
  float2 fo; fo.x = r0; fo.y = r1;
  *(float2*)(out + row + c0) = fo;
}

// ---------------------------------------------------------------------------
extern "C" void kernel_launch(void* const* d_in, const int* in_sizes, int n_in,
                              void* d_out, int out_size, void* d_ws, size_t ws_size,
                              hipStream_t stream) {
  const float* x        = (const float*)d_in[0];
  const float* qkv_w    = (const float*)d_in[1];
  const float* q_bias   = (const float*)d_in[2];
  const float* v_bias   = (const float*)d_in[3];
  const float* lscale   = (const float*)d_in[4];
  const float* cpb_w1   = (const float*)d_in[5];
  const float* cpb_b1   = (const float*)d_in[6];
  const float* cpb_w2   = (const float*)d_in[7];
  const float* proj_w   = (const float*)d_in[8];
  const float* proj_b   = (const float*)d_in[9];
  const float* n1w      = (const float*)d_in[10];
  const float* n1b      = (const float*)d_in[11];
  const float* n2w      = (const float*)d_in[12];
  const float* n2b      = (const float*)d_in[13];
  const float* fc1_w    = (const float*)d_in[14];
  const float* fc1_b    = (const float*)d_in[15];
  const float* fc2_w    = (const float*)d_in[16];
  const float* fc2_b    = (const float*)d_in[17];

  if (ws_size < 134217728u) return;
  char* ws = (char*)d_ws;
  u16* wqkv  = (u16*)(ws + 0);
  u16* wproj = (u16*)(ws + 1572864);
  u16* wfc1  = (u16*)(ws + 2097152);
  u16* wfc2  = (u16*)(ws + 4194304);
  u16* qkvh0 = (u16*)(ws + 6291456);
  u16* qkvh1 = (u16*)(ws + 56623104);
  u16* xbf   = (u16*)(ws + 106954752);
  u16* x1h   = (u16*)(ws + 6291456);
  u16* projo = (u16*)(ws + 39845888);
  u16* hbuf  = (u16*)(ws + 39845888);
  u16* fc2oh = (u16*)(ws + 107003904);
  u16* attnT  = (u16*)d_out;
  float* btbl = (float*)((char*)d_out + 33554432);
  float* out  = (float*)d_out;

  cpb_kernel<<<16, 64, 0, stream>>>(cpb_w1, cpb_b1, cpb_w2, btbl);
  cvt_kernel<<<768, 256, 0, stream>>>(qkv_w, wqkv, 196608);
  cvt_kernel<<<256, 256, 0, stream>>>(proj_w, wproj, 65536);
  cvt_kernel<<<1024, 256, 0, stream>>>(fc1_w, wfc1, 262144);
  cvt_kernel<<<1024, 256, 0, stream>>>(fc2_w, wfc2, 262144);

  for (int half = 0; half < 2; ++half) {
    cvt_kernel<<<8192, 256, 0, stream>>>(x + (size_t)half * 8388608, xbf, 2097152);
    gemm_bt<0><<<dim3(128, 12), 256, 0, stream>>>(
        xbf, wqkv, q_bias, v_bias, half ? qkvh1 : qkvh0,
        16384, 1536, 512, half * 16384);
  }
  attn_kernel<<<512, 256, 0, stream>>>(qkvh0, qkvh1, lscale, btbl, attnT);
  gemm_bt<1><<<dim3(256, 4), 256, 0, stream>>>(
      attnT, wproj, proj_b, nullptr, projo, 32768, 512, 512, 0);
  ln1_kernel<<<32768, 256, 0, stream>>>(projo, x, n1w, n1b, x1h);
  for (int half = 0; half < 2; ++half) {
    const u16* a2 = x1h + (size_t)half * 8388608;
    gemm_bt<2><<<dim3(128, 16), 256, 0, stream>>>(
        a2, wfc1, fc1_b, nullptr, hbuf, 16384, 2048, 512, 0);
    gemm_bt<3><<<dim3(128, 4), 256, 0, stream>>>(
        hbuf, wfc2, fc2_b, nullptr, fc2oh, 16384, 512, 2048, 0);
    ln2_kernel<<<16384, 256, 0, stream>>>(
        fc2oh, a2, n2w, n2b, out + (size_t)half * 8388608);
  }
}

// Round 6
// 510.329 us; speedup vs baseline: 1.7495x; 1.0783x over previous
//
#include <hip/hip_runtime.h>
#include <hip/hip_bf16.h>
#include <math.h>

typedef unsigned short u16;
typedef __bf16 bf16x8 __attribute__((ext_vector_type(8)));
typedef float f32x4 __attribute__((ext_vector_type(4)));
typedef unsigned short u16x8 __attribute__((ext_vector_type(8)));
typedef unsigned short u16x4 __attribute__((ext_vector_type(4)));
typedef unsigned short u16x2 __attribute__((ext_vector_type(2)));

#define DEV static __device__ __forceinline__

DEV float b2f(u16 v) { unsigned u = ((unsigned)v) << 16; return __builtin_bit_cast(float, u); }
DEV u16 f2bf(float f) {
  unsigned u = __builtin_bit_cast(unsigned, f);
  u += 0x7fffu + ((u >> 16) & 1u);
  return (u16)(u >> 16);
}

DEV void async16(const void* g, void* l) {
  __builtin_amdgcn_global_load_lds(
      (const __attribute__((address_space(1))) void*)g,
      (__attribute__((address_space(3))) void*)l, 16, 0, 0);
}

// ---------------------------------------------------------------------------
// f32 -> bf16 conversion
// ---------------------------------------------------------------------------
__global__ __launch_bounds__(256) void cvt_kernel(
    const float* __restrict__ in, u16* __restrict__ out, int n4)
{
  const int i = blockIdx.x * 256 + threadIdx.x;
  if (i < n4) {
    float4 v = ((const float4*)in)[i];
    u16x4 o;
    o[0] = f2bf(v.x); o[1] = f2bf(v.y); o[2] = f2bf(v.z); o[3] = f2bf(v.w);
    ((u16x4*)out)[i] = o;
  }
}

// ---------------------------------------------------------------------------
// CPB bias table: btbl[h][i][j] = 16*sigmoid(tbl[i-j+63][h])
// ---------------------------------------------------------------------------
__global__ __launch_bounds__(64) void cpb_kernel(
    const float* __restrict__ w1, const float* __restrict__ b1,
    const float* __restrict__ w2, float* __restrict__ btbl)
{
  const int h = blockIdx.x;
  const int lane = threadIdx.x;
  __shared__ float tbl[127];
  for (int r = lane; r < 127; r += 64) {
    float rv = (float)(r - 63) * (8.0f / 63.0f);
    float sgn = (rv > 0.f) ? 1.f : ((rv < 0.f) ? -1.f : 0.f);
    float t = sgn * log2f(fabsf(rv) + 1.f) * (1.f / 3.f);
    float acc = 0.f;
    for (int k = 0; k < 512; ++k) {
      float hid = fmaxf(t * w1[k] + b1[k], 0.f);
      acc += hid * w2[h * 512 + k];
    }
    tbl[r] = acc;
  }
  __syncthreads();
  for (int idx = lane; idx < 4096; idx += 64) {
    int i = idx >> 6, j = idx & 63;
    float v = tbl[i - j + 63];
    btbl[h * 4096 + idx] = 16.f / (1.f + __expf(-v));
  }
}

// ---------------------------------------------------------------------------
// GEMM  C[m][n] = sum_k A[m][k] * W[n][k]
// 2-phase double-buffered K-loop, BK=64, swizzled LDS (inverse-swz source +
// swz ds_read; rule #21). One barrier per K-tile.
// MODE 0: qkv (roll folded; scatter + q/v bias)
// MODE 1: proj (A = attnT [16][32768][32]; +bias)
// MODE 2: fc1 (+bias+tanh-gelu)   MODE 3: fc2 (+bias)
// ---------------------------------------------------------------------------
template <int MODE>
__global__ __launch_bounds__(256) void gemm_bt(
    const u16* __restrict__ A, const u16* __restrict__ W,
    const float* __restrict__ bias1, const float* __restrict__ bias2,
    u16* __restrict__ out, int M, int N, int K, int m_base)
{
  __shared__ __attribute__((aligned(16))) u16 lA[2][8192];   // [128][64] swz
  __shared__ __attribute__((aligned(16))) u16 lB[2][8192];
  const int tid = threadIdx.x;
  const int wid = tid >> 6;
  const int lane = tid & 63;
  const int m0 = blockIdx.x * 128;
  const int n0 = blockIdx.y * 128;
  const int wm = (wid >> 1) * 64;
  const int wn = (wid & 1) * 64;
  f32x4 acc[4][4] = {};

  // staging: per call 8 rows x 128B; lane l -> row +l>>3, 16B slot l&7.
  // LDS content swizzled: slot s of row r holds global k-block s^(r&7).
  const int srow8 = lane >> 3;
  const int kel = ((lane & 7) ^ srow8) * 8;      // global k elem offset to fetch

  auto stage = [&](int b, int k0) {
    #pragma unroll
    for (int cc = 0; cc < 4; ++cc) {
      const int rb = wid * 32 + cc * 8;
      const int r = rb + srow8;
      const u16* asrc;
      if constexpr (MODE == 0) {
        const int mg = m_base + m0 + r;
        const int bb = mg >> 12;
        const int p = mg & 4095;
        const long ga = (((long)bb << 12) + ((p + 32) & 4095)) - m_base;
        asrc = A + ga * (long)K + k0 + kel;
      } else if constexpr (MODE == 1) {
        const int kk = k0 + kel;
        asrc = A + (size_t)(kk >> 5) * 1048576 + (size_t)(m0 + r) * 32 + (kk & 31);
      } else {
        asrc = A + (long)(m0 + r) * K + k0 + kel;
      }
      async16(asrc, &lA[b][rb * 64]);
      async16(W + (long)(n0 + r) * K + k0 + kel, &lB[b][rb * 64]);
    }
  };

  const int NT = K >> 6;
  stage(0, 0);
  __syncthreads();
  int cur = 0;
  const int fr = lane & 15;
  const int hi = lane >> 4;
  const int fsw = fr & 7;
  for (int kt = 0; kt < NT; ++kt) {
    if (kt + 1 < NT) stage(cur ^ 1, (kt + 1) << 6);
    #pragma unroll
    for (int ks = 0; ks < 2; ++ks) {
      bf16x8 fa[4], fb[4];
      #pragma unroll
      for (int t = 0; t < 4; ++t) {
        const int ra = wm + t * 16 + fr;
        fa[t] = *(const bf16x8*)&lA[cur][ra * 64 + (((hi + 4 * ks) ^ fsw) << 3)];
        const int rbq = wn + t * 16 + fr;
        fb[t] = *(const bf16x8*)&lB[cur][rbq * 64 + (((hi + 4 * ks) ^ fsw) << 3)];
      }
      #pragma unroll
      for (int mi = 0; mi < 4; ++mi)
        #pragma unroll
        for (int ni = 0; ni < 4; ++ni)
          acc[mi][ni] = __builtin_amdgcn_mfma_f32_16x16x32_bf16(fa[mi], fb[ni], acc[mi][ni], 0, 0, 0);
    }
    __syncthreads();
    cur ^= 1;
  }

  const int lrow = (lane >> 4) * 4;
  const int lcol = lane & 15;
  #pragma unroll
  for (int mi = 0; mi < 4; ++mi) {
    #pragma unroll
    for (int ni = 0; ni < 4; ++ni) {
      const int n = n0 + wn + ni * 16 + lcol;
      #pragma unroll
      for (int r = 0; r < 4; ++r) {
        const int m = m0 + wm + mi * 16 + lrow + r;
        float v = acc[mi][ni][r];
        if constexpr (MODE == 0) {
          const int which = n >> 9, c = n & 511;
          const int hh = c >> 5, d = c & 31;
          float bias = (which == 0) ? bias1[c] : (which == 2 ? bias2[c] : 0.f);
          const int g = m >> 6, ii = m & 63;
          out[(size_t)which * 8388608 + (size_t)g * 32768 + hh * 2048 + ii * 32 + d] =
              f2bf(v + bias);
        } else if constexpr (MODE == 2) {
          float t = v + bias1[n];
          // tanh-form gelu: t * sigmoid(t*(c1 + c2*t^2)), max err ~3e-3
          float u = t * t;
          float z = t * (1.5957691216f + 0.0713548163f * u);
          float ge = t / (1.f + __expf(-z));
          out[(size_t)m * N + n] = f2bf(ge);
        } else {
          out[(size_t)m * N + n] = f2bf(v + bias1[n]);
        }
      }
    }
  }
}

// ---------------------------------------------------------------------------
// Attention (MFMA): 512 blocks x 4 waves; wave = (window gg, heads w*4+t).
// ---------------------------------------------------------------------------
__global__ __launch_bounds__(256) void attn_kernel(
    const u16* __restrict__ qkv0, const u16* __restrict__ qkv1,
    const float* __restrict__ ls, const float* __restrict__ btbl,
    u16* __restrict__ attnT)
{
  const int gg = blockIdx.x;
  const u16* qkv = (gg < 256) ? qkv0 : qkv1;
  const int g = gg & 255;
  const int w = threadIdx.x >> 6;
  const int lane = threadIdx.x & 63;
  __shared__ __attribute__((aligned(16))) u16 vt[4][2048];
  __shared__ __attribute__((aligned(16))) u16 pl[4][4096];
  const bool maskw = ((gg & 63) == 63);
  const int fr = lane & 15;
  const int fkq = (lane >> 4) * 8;
  const int crow = (lane >> 4) * 4;

  for (int t = 0; t < 4; ++t) {
    const int h = w * 4 + t;
    const size_t bgh = (size_t)g * 32768 + (size_t)h * 2048;

    {
      const u16x8* vp = (const u16x8*)(qkv + 16777216 + bgh + (size_t)lane * 32);
      #pragma unroll
      for (int c = 0; c < 4; ++c) {
        u16x8 vr = vp[c];
        #pragma unroll
        for (int e = 0; e < 8; ++e) {
          const int d = c * 8 + e;
          const int addr = d * 64 + (((lane >> 3) ^ (d & 7)) << 3) + (lane & 7);
          vt[w][addr] = vr[e];
        }
      }
    }

    const float scale = __expf(fminf(ls[h], 4.6051701859880914f));
    bf16x8 qa[4], kb[4];
    #pragma unroll
    for (int mi = 0; mi < 4; ++mi) {
      u16x8 raw = *(const u16x8*)(qkv + bgh + (size_t)(mi * 16 + fr) * 32 + fkq);
      float f[8]; float ssum = 0.f;
      #pragma unroll
      for (int e = 0; e < 8; ++e) { f[e] = b2f(raw[e]); ssum += f[e] * f[e]; }
      ssum += __shfl_xor(ssum, 16); ssum += __shfl_xor(ssum, 32);
      const float mul = scale / fmaxf(sqrtf(ssum), 1e-12f);
      u16x8 tmp;
      #pragma unroll
      for (int e = 0; e < 8; ++e) tmp[e] = f2bf(f[e] * mul);
      qa[mi] = __builtin_bit_cast(bf16x8, tmp);
    }
    #pragma unroll
    for (int ni = 0; ni < 4; ++ni) {
      u16x8 raw = *(const u16x8*)(qkv + 8388608 + bgh + (size_t)(ni * 16 + fr) * 32 + fkq);
      float f[8]; float ssum = 0.f;
      #pragma unroll
      for (int e = 0; e < 8; ++e) { f[e] = b2f(raw[e]); ssum += f[e] * f[e]; }
      ssum += __shfl_xor(ssum, 16); ssum += __shfl_xor(ssum, 32);
      const float mul = 1.f / fmaxf(sqrtf(ssum), 1e-12f);
      u16x8 tmp;
      #pragma unroll
      for (int e = 0; e < 8; ++e) tmp[e] = f2bf(f[e] * mul);
      kb[ni] = __builtin_bit_cast(bf16x8, tmp);
    }

    f32x4 s[4][4] = {};
    #pragma unroll
    for (int mi = 0; mi < 4; ++mi)
      #pragma unroll
      for (int ni = 0; ni < 4; ++ni)
        s[mi][ni] = __builtin_amdgcn_mfma_f32_16x16x32_bf16(qa[mi], kb[ni], s[mi][ni], 0, 0, 0);

    const float mh = scale + 16.f;
    float inv_[4][4];
    #pragma unroll
    for (int mi = 0; mi < 4; ++mi) {
      #pragma unroll
      for (int r = 0; r < 4; ++r) {
        const int row = mi * 16 + crow + r;
        float es = 0.f;
        #pragma unroll
        for (int ni = 0; ni < 4; ++ni) {
          const int col = ni * 16 + fr;
          float sv = s[mi][ni][r] + btbl[h * 4096 + row * 64 + col];
          if (maskw && ((row < 32) != (col < 32))) sv -= 100.f;
          const float e = __expf(sv - mh);
          s[mi][ni][r] = e;
          es += e;
        }
        es += __shfl_xor(es, 1); es += __shfl_xor(es, 2);
        es += __shfl_xor(es, 4); es += __shfl_xor(es, 8);
        inv_[mi][r] = 1.f / fmaxf(es, 1e-37f);
      }
    }

    #pragma unroll
    for (int mi = 0; mi < 4; ++mi)
      #pragma unroll
      for (int r = 0; r < 4; ++r) {
        const int row = mi * 16 + crow + r;
        #pragma unroll
        for (int ni = 0; ni < 4; ++ni) {
          const int col = ni * 16 + fr;
          const int addr = row * 64 + (((col >> 3) ^ (row & 7)) << 3) + (col & 7);
          pl[w][addr] = f2bf(s[mi][ni][r]);
        }
      }
    __syncthreads();

    f32x4 o[4][2] = {};
    #pragma unroll
    for (int ks = 0; ks < 2; ++ks) {
      bf16x8 vbf[2];
      #pragma unroll
      for (int np = 0; np < 2; ++np) {
        const int d = np * 16 + fr;
        const int jb = (lane >> 4) + ks * 4;
        vbf[np] = *(const bf16x8*)&vt[w][d * 64 + ((jb ^ (d & 7)) << 3)];
      }
      #pragma unroll
      for (int mp = 0; mp < 4; ++mp) {
        const int row = mp * 16 + fr;
        const int cb = (lane >> 4) + ks * 4;
        bf16x8 paf = *(const bf16x8*)&pl[w][row * 64 + ((cb ^ (row & 7)) << 3)];
        o[mp][0] = __builtin_amdgcn_mfma_f32_16x16x32_bf16(paf, vbf[0], o[mp][0], 0, 0, 0);
        o[mp][1] = __builtin_amdgcn_mfma_f32_16x16x32_bf16(paf, vbf[1], o[mp][1], 0, 0, 0);
      }
    }

    #pragma unroll
    for (int mp = 0; mp < 4; ++mp)
      #pragma unroll
      for (int r = 0; r < 4; ++r) {
        const int row = mp * 16 + crow + r;
        const float iv = inv_[mp][r];
        u16* op = attnT + (size_t)h * 1048576 + (size_t)(gg * 64 + row) * 32;
        op[fr]      = f2bf(o[mp][0][r] * iv);
        op[16 + fr] = f2bf(o[mp][1][r] * iv);
      }
    __syncthreads();
  }
}

// ---------------------------------------------------------------------------
// LN1: x1h = bf16( x + LN(roll_back(proj_out)) ),  x read as f32
// ---------------------------------------------------------------------------
__global__ __launch_bounds__(256) void ln1_kernel(
    const u16* __restrict__ proj, const float* __restrict__ x,
    const float* __restrict__ w, const float* __restrict__ bb,
    u16* __restrict__ x1h)
{
  const int t = blockIdx.x;
  const int b = t >> 12, l = t & 4095;
  const int p = (l - 32) & 4095;
  const size_t srow = (((size_t)b << 12) + p) << 9;
  const int c0 = threadIdx.x * 2;
  u16x2 pv = *(const u16x2*)(proj + srow + c0);
  float v0 = b2f(pv[0]), v1 = b2f(pv[1]);
  float s = v0 + v1, ss = v0 * v0 + v1 * v1;
  #pragma unroll
  for (int o = 32; o > 0; o >>= 1) { s += __shfl_down(s, o); ss += __shfl_down(ss, o); }
  __shared__ float red[8];
  const int wid = threadIdx.x >> 6, lane = threadIdx.x & 63;
  if (lane == 0) { red[wid] = s; red[4 + wid] = ss; }
  __syncthreads();
  const float S = red[0] + red[1] + red[2] + red[3];
  const float SS = red[4] + red[5] + red[6] + red[7];
  const float mean = S * (1.f / 512.f);
  const float var = SS * (1.f / 512.f) - mean * mean;
  const float rstd = rsqrtf(var + 1e-5f);
  const size_t orow = (size_t)t << 9;
  float2 xv = *(const float2*)(x + orow + c0);
  const float r0 = xv.x + (v0 - mean) * rstd * w[c0] + bb[c0];
  const float r1 = xv.y + (v1 - mean) * rstd * w[c0 + 1] + bb[c0 + 1];
  u16x2 ho; ho[0] = f2bf(r0); ho[1] = f2bf(r1);
  *(u16x2*)(x1h + orow + c0) = ho;
}

// ---------------------------------------------------------------------------
// LN2 (per half, local rows): out = f32( x1 + LN(fc2_out) )
// ---------------------------------------------------------------------------
__global__ __launch_bounds__(256) void ln2_kernel(
    const u16* __restrict__ fc2, const u16* __restrict__ x1h,
    const float* __restrict__ w, const float* __restrict__ bb,
    float* __restrict__ out)
{
  const int t = blockIdx.x;
  const size_t row = (size_t)t << 9;
  const int c0 = threadIdx.x * 2;
  u16x2 pv = *(const u16x2*)(fc2 + row + c0);
  float v0 = b2f(pv[0]), v1 = b2f(pv[1]);
  float s = v0 + v1, ss = v0 * v0 + v1 * v1;
  #pragma unroll
  for (int o = 32; o > 0; o >>= 1) { s += __shfl_down(s, o); ss += __shfl_down(ss, o); }
  __shared__ float red[8];
  const int wid = threadIdx.x >> 6, lane = threadIdx.x & 63;
  if (lane == 0) { red[wid] = s; red[4 + wid] = ss; }
  __syncthreads();
  const float S = red[0] + red[1] + red[2] + red[3];
  const float SS = red[4] + red[5] + red[6] + red[7];
  const float mean = S * (1.f / 512.f);
  const float var = SS * (1.f / 512.f) - mean * mean;
  const float rstd = rsqrtf(var + 1e-5f);
  u16x2 xv = *(const u16x2*)(x1h + row + c0);
  const float r0 = b2f(xv[0]) + (v0 - mean) * rstd * w[c0] + bb[c0];
  const float r1 = b2f(xv[1]) + (v1 - mean) * rstd * w[c0 + 1] + bb[c0 + 1];
  float2 fo; fo.x = r0; fo.y = r1;
  *(float2*)(out + row + c0) = fo;
}

// ---------------------------------------------------------------------------
extern "C" void kernel_launch(void* const* d_in, const int* in_sizes, int n_in,
                              void* d_out, int out_size, void* d_ws, size_t ws_size,
                              hipStream_t stream) {
  const float* x        = (const float*)d_in[0];
  const float* qkv_w    = (const float*)d_in[1];
  const float* q_bias   = (const float*)d_in[2];
  const float* v_bias   = (const float*)d_in[3];
  const float* lscale   = (const float*)d_in[4];
  const float* cpb_w1   = (const float*)d_in[5];
  const float* cpb_b1   = (const float*)d_in[6];
  const float* cpb_w2   = (const float*)d_in[7];
  const float* proj_w   = (const float*)d_in[8];
  const float* proj_b   = (const float*)d_in[9];
  const float* n1w      = (const float*)d_in[10];
  const float* n1b      = (const float*)d_in[11];
  const float* n2w      = (const float*)d_in[12];
  const float* n2b      = (const float*)d_in[13];
  const float* fc1_w    = (const float*)d_in[14];
  const float* fc1_b    = (const float*)d_in[15];
  const float* fc2_w    = (const float*)d_in[16];
  const float* fc2_b    = (const float*)d_in[17];

  if (ws_size < 134217728u) return;
  char* ws = (char*)d_ws;
  u16* wqkv  = (u16*)(ws + 0);
  u16* wproj = (u16*)(ws + 1572864);
  u16* wfc1  = (u16*)(ws + 2097152);
  u16* wfc2  = (u16*)(ws + 4194304);
  u16* qkvh0 = (u16*)(ws + 6291456);
  u16* qkvh1 = (u16*)(ws + 56623104);
  u16* xbf   = (u16*)(ws + 106954752);
  u16* x1h   = (u16*)(ws + 6291456);
  u16* projo = (u16*)(ws + 39845888);
  u16* hbuf  = (u16*)(ws + 39845888);
  u16* fc2oh = (u16*)(ws + 107003904);
  u16* attnT  = (u16*)d_out;
  float* btbl = (float*)((char*)d_out + 33554432);
  float* out  = (float*)d_out;

  cpb_kernel<<<16, 64, 0, stream>>>(cpb_w1, cpb_b1, cpb_w2, btbl);
  cvt_kernel<<<768, 256, 0, stream>>>(qkv_w, wqkv, 196608);
  cvt_kernel<<<256, 256, 0, stream>>>(proj_w, wproj, 65536);
  cvt_kernel<<<1024, 256, 0, stream>>>(fc1_w, wfc1, 262144);
  cvt_kernel<<<1024, 256, 0, stream>>>(fc2_w, wfc2, 262144);

  for (int half = 0; half < 2; ++half) {
    cvt_kernel<<<8192, 256, 0, stream>>>(x + (size_t)half * 8388608, xbf, 2097152);
    gemm_bt<0><<<dim3(128, 12), 256, 0, stream>>>(
        xbf, wqkv, q_bias, v_bias, half ? qkvh1 : qkvh0,
        16384, 1536, 512, half * 16384);
  }
  attn_kernel<<<512, 256, 0, stream>>>(qkvh0, qkvh1, lscale, btbl, attnT);
  gemm_bt<1><<<dim3(256, 4), 256, 0, stream>>>(
      attnT, wproj, proj_b, nullptr, projo, 32768, 512, 512, 0);
  ln1_kernel<<<32768, 256, 0, stream>>>(projo, x, n1w, n1b, x1h);
  for (int half = 0; half < 2; ++half) {
    const u16* a2 = x1h + (size_t)half * 8388608;
    gemm_bt<2><<<dim3(128, 16), 256, 0, stream>>>(
        a2, wfc1, fc1_b, nullptr, hbuf, 16384, 2048, 512, 0);
    gemm_bt<3><<<dim3(128, 4), 256, 0, stream>>>(
        hbuf, wfc2, fc2_b, nullptr, fc2oh, 16384, 512, 2048, 0);
    ln2_kernel<<<16384, 256, 0, stream>>>(
        fc2oh, a2, n2w, n2b, out + (size_t)half * 8388608);
  }
}